// Round 11
// baseline (46.888 us; speedup 1.0000x reference)
//
#include <hip/hip_runtime.h>
#include <hip/hip_bf16.h>

#define CIN   64
#define COUT  128
#define TT    256
#define VV    25
#define TV    (TT * VV)   // 6400
#define KW    9
#define PAD   4
#define YROW  28          // padded bf16 y row: 56B
#define YSTR  (TT * YROW) // 7168 shorts per (n,c) plane

typedef __attribute__((ext_vector_type(8))) short short8;   // 8 bf16 (4 VGPRs)
typedef __attribute__((ext_vector_type(4))) float f32x4;

__device__ __forceinline__ unsigned f2b(float f) {          // fp32 -> bf16 bits (RNE)
    unsigned u = __builtin_bit_cast(unsigned, f);
    return (u + 0x7FFFu + ((u >> 16) & 1u)) >> 16;
}
__device__ __forceinline__ float lof(unsigned u) {          // low bf16 -> f32
    return __builtin_bit_cast(float, u << 16);
}
__device__ __forceinline__ float hif(unsigned u) {          // high bf16 -> f32
    return __builtin_bit_cast(float, u & 0xffff0000u);
}
// conv LDS tile swizzle: [row][128B], XOR slot with (row&7)
__device__ __forceinline__ int swz(int row, int cbyte) {
    return row * 128 + ((cbyte & ~15) ^ ((row & 7) << 4)) + (cbyte & 15);
}

// ---------------- Kernel A: 1x1 conv + BN via bf16 MFMA (unchanged) ----------------
__global__ __launch_bounds__(256) void conv_mfma(
    const float* __restrict__ x, const float* __restrict__ w,
    const float* __restrict__ cb, const float* __restrict__ gamma,
    const float* __restrict__ beta, const float* __restrict__ rm,
    const float* __restrict__ rv, unsigned short* __restrict__ y)
{
    __shared__ __align__(16) unsigned short Wl[COUT * 64];   // 16 KB, swizzled
    __shared__ __align__(16) unsigned short Xl[128 * 64];    // 16 KB, swizzled [pos][c]
    __shared__ float sc[COUT];
    __shared__ float of[COUT];

    const int pc  = blockIdx.x;       // 0..49
    const int n   = blockIdx.y;       // 0..15
    const int tid = threadIdx.x;
    const int posbase = pc * 128;

    if (tid < COUT) {
        const float s = gamma[tid] * rsqrtf(rv[tid] + 1e-5f);
        sc[tid] = s;
        of[tid] = cb[tid] * s + beta[tid] - rm[tid] * s;
    }
    for (int idx = tid; idx < 2048; idx += 256) {
        const int c4 = idx & 15, o = idx >> 4;
        const f32x4 wv = *(const f32x4*)(w + o * 64 + c4 * 4);
        uint2 pk;
        pk.x = f2b(wv.x) | (f2b(wv.y) << 16);
        pk.y = f2b(wv.z) | (f2b(wv.w) << 16);
        *(uint2*)((char*)Wl + swz(o, c4 * 8)) = pk;
    }
    for (int idx = tid; idx < 2048; idx += 256) {
        const int pos = idx & 127, c4 = idx >> 7;
        const float* xp = x + (size_t)n * CIN * TV + (size_t)(c4 * 4) * TV + posbase + pos;
        const float a0 = xp[0], a1 = xp[TV], a2 = xp[2 * TV], a3 = xp[3 * TV];
        uint2 pk;
        pk.x = f2b(a0) | (f2b(a1) << 16);
        pk.y = f2b(a2) | (f2b(a3) << 16);
        *(uint2*)((char*)Xl + swz(pos, c4 * 8)) = pk;
    }
    __syncthreads();

    const int wv_ = tid >> 6, lane = tid & 63;
    const int lr = lane & 15, lh = lane >> 4;   // lh in 0..3

    short8 afr[2][2];
#pragma unroll
    for (int m0 = 0; m0 < 2; ++m0)
#pragma unroll
        for (int kh = 0; kh < 2; ++kh)
            afr[m0][kh] = *(const short8*)((const char*)Wl +
                              swz(wv_ * 32 + m0 * 16 + lr, kh * 64 + lh * 16));

    f32x4 acc[2][8];
#pragma unroll
    for (int m0 = 0; m0 < 2; ++m0)
#pragma unroll
        for (int n0 = 0; n0 < 8; ++n0) acc[m0][n0] = (f32x4){0.f, 0.f, 0.f, 0.f};

#pragma unroll
    for (int n0 = 0; n0 < 8; ++n0) {
        const int prow = n0 * 16 + lr;
        const short8 b0 = *(const short8*)((const char*)Xl + swz(prow, lh * 16));
        const short8 b1 = *(const short8*)((const char*)Xl + swz(prow, 64 + lh * 16));
#pragma unroll
        for (int m0 = 0; m0 < 2; ++m0) {
            acc[m0][n0] = __builtin_amdgcn_mfma_f32_16x16x32_bf16(afr[m0][0], b0, acc[m0][n0], 0, 0, 0);
            acc[m0][n0] = __builtin_amdgcn_mfma_f32_16x16x32_bf16(afr[m0][1], b1, acc[m0][n0], 0, 0, 0);
        }
    }

    float scv[2][4], ofv[2][4];
#pragma unroll
    for (int m0 = 0; m0 < 2; ++m0)
#pragma unroll
        for (int r = 0; r < 4; ++r) {
            const int o = wv_ * 32 + m0 * 16 + lh * 4 + r;
            scv[m0][r] = sc[o];
            ofv[m0][r] = of[o];
        }

    const size_t ybase = (size_t)(n * COUT) * YSTR;
#pragma unroll
    for (int m0 = 0; m0 < 2; ++m0)
#pragma unroll
        for (int n0 = 0; n0 < 8; ++n0)
#pragma unroll
            for (int r = 0; r < 4; ++r) {
                const int o = wv_ * 32 + m0 * 16 + lh * 4 + r;
                const int pos = posbase + n0 * 16 + lr;
                const int t = pos / 25;
                const int v = pos - t * 25;
                const float val = acc[m0][n0][r] * scv[m0][r] + ofv[m0][r];
                y[ybase + (size_t)o * YSTR + t * YROW + v] = (unsigned short)f2b(val);
            }
}

// ---------------- Kernel B: temporal-window attention (half-T blocks) ----------------
// 4096 blocks (nc x 2 halves) x 128 threads, t = th*128 + tid.
// Tile = 136 rows x 56B = 7.6 KB (4-row halo each side; interior halos are
// REAL rows loaded from the neighboring half, boundary halos zero).
// Lane->row stride 1: 16 lanes' uint2 starts = 14*l mod 32 = 16 distinct even
// values -> all 32 banks tiled exactly -> conflict-free.
// Smaller blocks -> 6 co-resident blocks/CU in different phases (convoy-break).
#define LOADROW(lr, dst)                                                    \
    {                                                                       \
        const int ub_ = 7 * (lr);                                           \
        const uint2 r0_ = tl2[ub_],     r1_ = tl2[ub_ + 1];                 \
        const uint2 r2_ = tl2[ub_ + 2], r3_ = tl2[ub_ + 3];                 \
        const uint2 r4_ = tl2[ub_ + 4], r5_ = tl2[ub_ + 5];                 \
        const unsigned l_ = tlu[14 * (lr) + 12];                            \
        (dst)[0]  = lof(r0_.x); (dst)[1]  = hif(r0_.x);                     \
        (dst)[2]  = lof(r0_.y); (dst)[3]  = hif(r0_.y);                     \
        (dst)[4]  = lof(r1_.x); (dst)[5]  = hif(r1_.x);                     \
        (dst)[6]  = lof(r1_.y); (dst)[7]  = hif(r1_.y);                     \
        (dst)[8]  = lof(r2_.x); (dst)[9]  = hif(r2_.x);                     \
        (dst)[10] = lof(r2_.y); (dst)[11] = hif(r2_.y);                     \
        (dst)[12] = lof(r3_.x); (dst)[13] = hif(r3_.x);                     \
        (dst)[14] = lof(r3_.y); (dst)[15] = hif(r3_.y);                     \
        (dst)[16] = lof(r4_.x); (dst)[17] = hif(r4_.x);                     \
        (dst)[18] = lof(r4_.y); (dst)[19] = hif(r4_.y);                     \
        (dst)[20] = lof(r5_.x); (dst)[21] = hif(r5_.x);                     \
        (dst)[22] = lof(r5_.y); (dst)[23] = hif(r5_.y);                     \
        (dst)[24] = lof(l_);                                                \
    }

__global__ __launch_bounds__(128) void attn_kernel(
    const unsigned short* __restrict__ y, const float* __restrict__ att0,
    float* __restrict__ out)
{
    __shared__ __align__(16) float sm[128 * VV];   // 12.8 KB: tile (7.6 KB) then overlay
    __shared__ float a0s[KW];

    uint4* tl4 = (uint4*)sm;                  // tile: 476 uint4 = 7616 B
    const uint2* tl2 = (const uint2*)sm;
    const unsigned* tlu = (const unsigned*)sm;

    const int bid = blockIdx.x;
    const int nc  = bid >> 1;         // n*COUT + c
    const int th  = bid & 1;          // t-half
    const int c   = nc & (COUT - 1);
    const int tid = threadIdx.x;

    if (tid < KW) a0s[tid] = att0[c * KW + tid];

    // stage 476 uint4: rows [th*128-4, th*128+132); boundary halo zeroed,
    // interior halo loaded from the neighbor half's real rows.
    const uint4* yg = (const uint4*)(y + (size_t)nc * YSTR);
    if (th == 0) {
#pragma unroll
        for (int i = 0; i < 4; ++i) {
            const int ci = tid + i * 128;
            if (ci < 476)
                tl4[ci] = (ci < 14) ? make_uint4(0, 0, 0, 0) : yg[ci - 14];
        }
    } else {
#pragma unroll
        for (int i = 0; i < 4; ++i) {
            const int ci = tid + i * 128;
            if (ci < 476)
                tl4[ci] = (ci >= 462) ? make_uint4(0, 0, 0, 0) : yg[434 + ci];
        }
    }
    __syncthreads();

    // local center row = tid + 4
    float q[25];
    LOADROW(tid + 4, q);

    float osm[25], oa0[25];
    float den;
    {   // j = 4: self term (row == q, no LDS read)
        float d0 = 0.f, d1 = 0.f;
#pragma unroll
        for (int v = 0; v < 12; ++v)  d0 = fmaf(q[v], q[v], d0);
#pragma unroll
        for (int v = 12; v < 25; ++v) d1 = fmaf(q[v], q[v], d1);
        const float e = __expf((d0 + d1) * (1.f / 25.f));
        den = e;
        const float a = a0s[4];
#pragma unroll
        for (int v = 0; v < 25; ++v) { osm[v] = e * q[v]; oa0[v] = a * q[v]; }
    }

#pragma unroll
    for (int j = 0; j < KW; ++j) {
        if (j == 4) continue;
        float row[25];
        LOADROW(tid + j, row);
        float d0 = 0.f, d1 = 0.f;
#pragma unroll
        for (int v = 0; v < 12; ++v)  d0 = fmaf(row[v], q[v], d0);
#pragma unroll
        for (int v = 12; v < 25; ++v) d1 = fmaf(row[v], q[v], d1);
        const float e = __expf((d0 + d1) * (1.f / 25.f));
        den += e;
        const float a = a0s[j];
#pragma unroll
        for (int v = 0; v < 25; ++v) {
            osm[v] = fmaf(e, row[v], osm[v]);
            oa0[v] = fmaf(a, row[v], oa0[v]);
        }
    }

    const float inv = 1.f / den;

    // ---- overlay pack (scalar b32: odd dword stride -> conflict-light) ----
    __syncthreads();
    {
        float* dst = &sm[tid * 25];
#pragma unroll
        for (int v = 0; v < 25; ++v) dst[v] = fmaf(osm[v], inv, oa0[v]);
    }
    __syncthreads();

    // ---- block-contiguous float4 stores: full 64B lines per instruction ----
    {
        float4* og = (float4*)(out + (size_t)nc * TV + th * 128 * VV);
        const float4* sm4 = (const float4*)sm;
#pragma unroll
        for (int i = 0; i < 7; ++i) {
            const int ci = tid + i * 128;
            if (ci < 128 * VV / 4) og[ci] = sm4[ci];
        }
    }
}

extern "C" void kernel_launch(void* const* d_in, const int* in_sizes, int n_in,
                              void* d_out, int out_size, void* d_ws, size_t ws_size,
                              hipStream_t stream)
{
    const float* x     = (const float*)d_in[0];
    const float* w     = (const float*)d_in[1];
    const float* cb    = (const float*)d_in[2];
    const float* gamma = (const float*)d_in[3];
    const float* beta  = (const float*)d_in[4];
    const float* rm    = (const float*)d_in[5];
    const float* rv    = (const float*)d_in[6];
    const float* att0  = (const float*)d_in[7];
    float* out = (float*)d_out;
    unsigned short* y = (unsigned short*)d_ws;   // 2048*7168*2 = 29.4 MB padded bf16

    dim3 gA(TV / 128, 16);   // 50 x 16
    conv_mfma<<<gA, 256, 0, stream>>>(x, w, cb, gamma, beta, rm, rv, y);

    dim3 gB(2 * 16 * COUT);  // 4096 half-T blocks
    attn_kernel<<<gB, 128, 0, stream>>>(y, att0, out);
}